// Round 1
// baseline (131.132 us; speedup 1.0000x reference)
//
#include <hip/hip_runtime.h>

typedef __attribute__((ext_vector_type(8))) __bf16  bf16x8;
typedef __attribute__((ext_vector_type(8))) short   short8;
typedef __attribute__((ext_vector_type(4))) short   short4v;
typedef __attribute__((ext_vector_type(4))) float   f32x4;

#define DM   512
#define BM   128
#define BN   128
#define BK   32
#define LDSP 40          // padded LDS row stride in shorts (32 + 8 -> ~2-way bank aliasing, free)

__device__ __forceinline__ short f2bf(float f) {
  union { float f; unsigned u; } v; v.f = f;
  unsigned r = v.u + 0x7fffu + ((v.u >> 16) & 1u);   // round-to-nearest-even
  return (short)(r >> 16);
}

// Fold softmax(taps) + depthwise conv into per-head matrix G[h][e][d] (bf16).
__global__ void build_g_kernel(const float* __restrict__ w,
                               const float* __restrict__ fcw,
                               short* __restrict__ G) {
  int idx = blockIdx.x * 256 + threadIdx.x;   // 8*512*512 total
  int h = idx >> 18;
  int e = (idx >> 9) & 511;
  int d = idx & 511;
  float w0 = w[h*3+0], w1 = w[h*3+1], w2 = w[h*3+2];
  float mx = fmaxf(w0, fmaxf(w1, w2));
  float e0 = __expf(w0-mx), e1 = __expf(w1-mx), e2 = __expf(w2-mx);
  float inv = 1.0f / (e0 + e1 + e2);
  const float* row = fcw + e * DM;
  float acc = e1 * inv * row[d];
  if (d < DM-1) acc += e0 * inv * row[d+1];   // tap k=0 reads x[d-1] => contributes fc_w[e][d+1] to G[.,d]
  if (d > 0)    acc += e2 * inv * row[d-1];   // tap k=2
  G[idx] = f2bf(acc);
}

// y[R, e] = sum_d x[R,d] * G[R%8][e,d]
// Head-grouped GEMM: block = (head h, row-tile mt of 128 rows with R = h+8*t, col-tile nt of 128 e)
__global__ __launch_bounds__(256) void gemm_kernel(const float* __restrict__ x,
                                                   const short* __restrict__ G,
                                                   float* __restrict__ out) {
  int bid = blockIdx.x;
  int h  = bid >> 8;          // 256 blocks per head (64 mtiles * 4 ntiles)
  int mt = (bid >> 2) & 63;
  int nt = bid & 3;
  int tid  = threadIdx.x;
  int lane = tid & 63;
  int wid  = tid >> 6;
  int wr = wid >> 1, wc = wid & 1;     // 2x2 wave grid, each wave owns 64x64

  __shared__ short Alds[BM * LDSP];
  __shared__ short Blds[BN * LDSP];

  const short* Gh = G + h * DM * DM + nt * BN * DM;

  f32x4 acc[4][4] = {};

  for (int k0 = 0; k0 < DM; k0 += BK) {
    __syncthreads();   // protect LDS from previous iteration's reads

    // Stage A: 128 rows x 32 f32 -> bf16. 1024 chunks of 4 floats, 4/thread.
    #pragma unroll
    for (int i = 0; i < 4; ++i) {
      int c = tid + 256 * i;
      int r = c >> 3, q = c & 7;
      int R = h + 8 * (mt * BM + r);
      const float4 v = *(const float4*)(x + (size_t)R * DM + k0 + q * 4);
      short4v s;
      s.x = f2bf(v.x); s.y = f2bf(v.y); s.z = f2bf(v.z); s.w = f2bf(v.w);
      *(short4v*)&Alds[r * LDSP + q * 4] = s;
    }
    // Stage B: 128 e-rows x 32 bf16. 512 chunks of 8 shorts, 2/thread.
    #pragma unroll
    for (int i = 0; i < 2; ++i) {
      int c = tid + 256 * i;
      int r = c >> 2, q = c & 3;
      short8 v = *(const short8*)(Gh + r * DM + k0 + q * 8);
      *(short8*)&Blds[r * LDSP + q * 8] = v;
    }
    __syncthreads();

    // Fragments: A row = lane&15 (+16m), k = (lane>>4)*8..+8 ; same for B (row = e-col of output)
    bf16x8 af[4], bfr[4];
    #pragma unroll
    for (int m = 0; m < 4; ++m)
      af[m] = *(const bf16x8*)&Alds[(wr*64 + m*16 + (lane & 15)) * LDSP + (lane >> 4) * 8];
    #pragma unroll
    for (int n = 0; n < 4; ++n)
      bfr[n] = *(const bf16x8*)&Blds[(wc*64 + n*16 + (lane & 15)) * LDSP + (lane >> 4) * 8];

    #pragma unroll
    for (int m = 0; m < 4; ++m)
      #pragma unroll
      for (int n = 0; n < 4; ++n)
        acc[m][n] = __builtin_amdgcn_mfma_f32_16x16x32_bf16(af[m], bfr[n], acc[m][n], 0, 0, 0);
  }

  // Epilogue: C/D layout col = lane&15, row = (lane>>4)*4 + j
  int e0 = nt * BN + wc * 64 + (lane & 15);
  #pragma unroll
  for (int m = 0; m < 4; ++m) {
    int tbase = mt * BM + wr * 64 + m * 16 + ((lane >> 4) << 2);
    #pragma unroll
    for (int j = 0; j < 4; ++j) {
      int R = h + 8 * (tbase + j);
      float* orow = out + (size_t)R * DM + e0;
      #pragma unroll
      for (int n = 0; n < 4; ++n)
        orow[n * 16] = acc[m][n][j];
    }
  }
}

extern "C" void kernel_launch(void* const* d_in, const int* in_sizes, int n_in,
                              void* d_out, int out_size, void* d_ws, size_t ws_size,
                              hipStream_t stream) {
  const float* x   = (const float*)d_in[0];
  const float* w   = (const float*)d_in[1];
  const float* fcw = (const float*)d_in[2];
  float* out = (float*)d_out;
  short* G   = (short*)d_ws;   // 8*512*512 bf16 = 4 MiB

  hipLaunchKernelGGL(build_g_kernel, dim3((8 * DM * DM) / 256), dim3(256), 0, stream,
                     w, fcw, G);
  hipLaunchKernelGGL(gemm_kernel, dim3(8 * 64 * 4), dim3(256), 0, stream,
                     x, G, out);
}

// Round 2
// 129.366 us; speedup vs baseline: 1.0137x; 1.0137x over previous
//
#include <hip/hip_runtime.h>

typedef __attribute__((ext_vector_type(8))) __bf16  bf16x8;
typedef __attribute__((ext_vector_type(8))) short   short8;
typedef __attribute__((ext_vector_type(4))) float   f32x4;

#define DM   512
#define BM   128
#define BN   128
#define BK   64
#define NT   (DM/BN)          // 4 n-tiles
#define NKT  (DM/BK)          // 8 k-tiles
#define TILE_B_BYTES (BN*BK*2)   // 16 KiB per B tile image

__device__ __forceinline__ short f2bf(float f) {
  union { float f; unsigned u; } v; v.f = f;
  unsigned r = v.u + 0x7fffu + ((v.u >> 16) & 1u);   // round-to-nearest-even
  return (short)(r >> 16);
}

// XOR swizzle: byte offset within a [rows][64 bf16] tile (128B row stride).
// Spreads the 16-lane same-column ds_read_b128 across 8 distinct 16B slots.
__device__ __forceinline__ int swz(int r, int cbyte) {
  return (r * 128 + cbyte) ^ ((r & 7) << 4);
}

// Fold softmax(taps) + depthwise conv into per-head matrix G[h][e][d],
// stored as pre-swizzled per-(h,nt,kt) LDS tile images so the GEMM can
// global_load_lds them linearly and ds_read them with swz().
__global__ void build_g_kernel(const float* __restrict__ w,
                               const float* __restrict__ fcw,
                               short* __restrict__ Gt) {
  int idx = blockIdx.x * 256 + threadIdx.x;   // 8*512*512 total
  int h = idx >> 18;
  int e = (idx >> 9) & 511;
  int d = idx & 511;
  float w0 = w[h*3+0], w1 = w[h*3+1], w2 = w[h*3+2];
  float mx = fmaxf(w0, fmaxf(w1, w2));
  float e0 = __expf(w0-mx), e1 = __expf(w1-mx), e2 = __expf(w2-mx);
  float inv = 1.0f / (e0 + e1 + e2);
  const float* row = fcw + e * DM;
  float acc = e1 * inv * row[d];
  if (d < DM-1) acc += e0 * inv * row[d+1];   // tap k=0 reads x[d-1] => fc_w[e][d+1]
  if (d > 0)    acc += e2 * inv * row[d-1];   // tap k=2
  int nt = e >> 7, r = e & 127;
  int kt = d >> 6, c = d & 63;
  char* tile = (char*)Gt + (size_t)((h * NT + nt) * NKT + kt) * TILE_B_BYTES;
  *(short*)(tile + swz(r, c * 2)) = f2bf(acc);
}

// y[R, e] = sum_d x[R,d] * G[R%8][e,d]; R = h + 8*t
__global__ __launch_bounds__(256, 4) void gemm_kernel(const float* __restrict__ x,
                                                      const short* __restrict__ Gt,
                                                      float* __restrict__ out) {
  // XCD-aware swizzle: 2048 blocks, 8 XCDs, 2048%8==0 -> simple bijective form.
  int bid = blockIdx.x;
  int swb = (bid & 7) * 256 + (bid >> 3);
  int h  = swb >> 8;          // 256 blocks per head (64 mtiles * 4 ntiles)
  int mt = (swb >> 2) & 63;
  int nt = swb & 3;
  int tid  = threadIdx.x;
  int lane = tid & 63;
  int wid  = tid >> 6;
  int wr = wid >> 1, wc = wid & 1;     // 2x2 wave grid, each wave owns 64x64

  __shared__ short Alds[BM * BK];   // 16 KiB, swizzled image
  __shared__ short Blds[BN * BK];   // 16 KiB, swizzled image (exact copy of Gt tile)

  const char* Bsrc0 = (const char*)Gt + (size_t)(h * NT + nt) * NKT * TILE_B_BYTES;

  f32x4 acc[4][4] = {};

  for (int kt = 0; kt < NKT; ++kt) {
    __syncthreads();   // protect LDS from previous iteration's reads

    // --- B: async global->LDS, 16 KiB tile, 4 x 16B per thread, linear copy.
    {
      const char* src = Bsrc0 + kt * TILE_B_BYTES;
      int wbase = (tid >> 6) << 10;    // wave-uniform LDS base (wave * 1024B)
      #pragma unroll
      for (int p = 0; p < 4; ++p) {
        __builtin_amdgcn_global_load_lds(
            (const void*)(src + p * 4096 + tid * 16),
            (void*)((char*)Blds + p * 4096 + wbase),
            16, 0, 0);
      }
    }
    // --- A: reg-staged f32->bf16, 1024 16B-chunks, 4 per thread, swizzled ds_write.
    {
      int R0 = mt * BM;
      #pragma unroll
      for (int i = 0; i < 4; ++i) {
        int c = tid + 256 * i;
        int r = c >> 3, s = c & 7;
        const float* xr = x + (size_t)(h + 8 * (R0 + r)) * DM + kt * BK + s * 8;
        float4 v0 = *(const float4*)xr;
        float4 v1 = *(const float4*)(xr + 4);
        short8 sv;
        sv[0]=f2bf(v0.x); sv[1]=f2bf(v0.y); sv[2]=f2bf(v0.z); sv[3]=f2bf(v0.w);
        sv[4]=f2bf(v1.x); sv[5]=f2bf(v1.y); sv[6]=f2bf(v1.z); sv[7]=f2bf(v1.w);
        *(short8*)((char*)Alds + swz(r, s * 16)) = sv;
      }
    }
    __syncthreads();   // drains vmcnt (global_load_lds) + lgkm (ds_write)

    // --- Fragments + MFMA, per 32-wide k-slice to cap live VGPRs.
    #pragma unroll
    for (int kk = 0; kk < 2; ++kk) {
      bf16x8 af[4], bfr[4];
      #pragma unroll
      for (int m = 0; m < 4; ++m) {
        int r = wr * 64 + m * 16 + (lane & 15);
        af[m] = *(const bf16x8*)((const char*)Alds + swz(r, kk * 64 + (lane >> 4) * 16));
      }
      #pragma unroll
      for (int n = 0; n < 4; ++n) {
        int r = wc * 64 + n * 16 + (lane & 15);
        bfr[n] = *(const bf16x8*)((const char*)Blds + swz(r, kk * 64 + (lane >> 4) * 16));
      }
      #pragma unroll
      for (int m = 0; m < 4; ++m)
        #pragma unroll
        for (int n = 0; n < 4; ++n)
          acc[m][n] = __builtin_amdgcn_mfma_f32_16x16x32_bf16(af[m], bfr[n], acc[m][n], 0, 0, 0);
    }
  }

  // Epilogue: C/D layout col = lane&15, row = (lane>>4)*4 + j
  int e0 = nt * BN + wc * 64 + (lane & 15);
  #pragma unroll
  for (int m = 0; m < 4; ++m) {
    int tbase = mt * BM + wr * 64 + m * 16 + ((lane >> 4) << 2);
    #pragma unroll
    for (int j = 0; j < 4; ++j) {
      int R = h + 8 * (tbase + j);
      float* orow = out + (size_t)R * DM + e0;
      #pragma unroll
      for (int n = 0; n < 4; ++n)
        orow[n * 16] = acc[m][n][j];
    }
  }
}

extern "C" void kernel_launch(void* const* d_in, const int* in_sizes, int n_in,
                              void* d_out, int out_size, void* d_ws, size_t ws_size,
                              hipStream_t stream) {
  const float* x   = (const float*)d_in[0];
  const float* w   = (const float*)d_in[1];
  const float* fcw = (const float*)d_in[2];
  float* out = (float*)d_out;
  short* Gt  = (short*)d_ws;   // 8*4*8 tiles * 16 KiB = 4 MiB, pre-swizzled

  hipLaunchKernelGGL(build_g_kernel, dim3((8 * DM * DM) / 256), dim3(256), 0, stream,
                     w, fcw, Gt);
  hipLaunchKernelGGL(gemm_kernel, dim3(8 * 64 * NT), dim3(256), 0, stream,
                     x, Gt, out);
}

// Round 3
// 88.831 us; speedup vs baseline: 1.4762x; 1.4563x over previous
//
#include <hip/hip_runtime.h>

typedef __attribute__((ext_vector_type(8))) __bf16  bf16x8;
typedef __attribute__((ext_vector_type(8))) short   short8;
typedef __attribute__((ext_vector_type(4))) float   f32x4;

#define DM   512
#define BM   128
#define BN   128
#define BK   64
#define NT   (DM/BN)          // 4 n-tiles
#define NKT  (DM/BK)          // 8 k-tiles
#define TILE_B_BYTES (BN*BK*2)   // 16 KiB per B tile image

__device__ __forceinline__ short f2bf(float f) {
  union { float f; unsigned u; } v; v.f = f;
  unsigned r = v.u + 0x7fffu + ((v.u >> 16) & 1u);   // round-to-nearest-even
  return (short)(r >> 16);
}

// XOR swizzle: byte offset within a [rows][64 bf16] tile (128B row stride).
__device__ __forceinline__ int swz(int r, int cbyte) {
  return (r * 128 + cbyte) ^ ((r & 7) << 4);
}

// Fold softmax(taps) + depthwise conv into per-head matrix G[h][e][d],
// stored as pre-swizzled per-(h,nt,kt) LDS tile images (rule #21: source
// permutation == read permutation, linear global_load_lds dest).
__global__ void build_g_kernel(const float* __restrict__ w,
                               const float* __restrict__ fcw,
                               short* __restrict__ Gt) {
  int idx = blockIdx.x * 256 + threadIdx.x;   // 8*512*512 total
  int h = idx >> 18;
  int e = (idx >> 9) & 511;
  int d = idx & 511;
  float w0 = w[h*3+0], w1 = w[h*3+1], w2 = w[h*3+2];
  float mx = fmaxf(w0, fmaxf(w1, w2));
  float e0 = __expf(w0-mx), e1 = __expf(w1-mx), e2 = __expf(w2-mx);
  float inv = 1.0f / (e0 + e1 + e2);
  const float* row = fcw + e * DM;
  float acc = e1 * inv * row[d];
  if (d < DM-1) acc += e0 * inv * row[d+1];
  if (d > 0)    acc += e2 * inv * row[d-1];
  int nt = e >> 7, r = e & 127;
  int kt = d >> 6, c = d & 63;
  char* tile = (char*)Gt + (size_t)((h * NT + nt) * NKT + kt) * TILE_B_BYTES;
  *(short*)(tile + swz(r, c * 2)) = f2bf(acc);
}

// y[R, e] = sum_d x[R,d] * G[R%8][e,d]; R = h + 8*t
__global__ __launch_bounds__(256, 2) void gemm_kernel(const float* __restrict__ x,
                                                      const short* __restrict__ Gt,
                                                      float* __restrict__ out) {
  // XCD swizzle: 2048 blocks, head h == XCD, mt-pairs adjacent across nt.
  int bid = blockIdx.x;
  int swb = (bid & 7) * 256 + (bid >> 3);
  int h  = swb >> 8;
  int mt = (swb >> 2) & 63;
  int nt = swb & 3;
  int tid  = threadIdx.x;
  int lane = tid & 63;
  int wid  = tid >> 6;
  int wr = wid >> 1, wc = wid & 1;     // 2x2 wave grid, 64x64 per wave

  __shared__ short Alds[2][BM * BK];   // 2 x 16 KiB, swizzled images
  __shared__ short Blds[2][BN * BK];   // 2 x 16 KiB

  const char* Bsrc0 = (const char*)Gt + (size_t)(h * NT + nt) * NKT * TILE_B_BYTES;
  int wbase = wid << 10;               // wave-uniform LDS byte base for gload_lds

  // --- staging helpers -------------------------------------------------
  float4 ap[8];                        // A prefetch registers (32 VGPR)

  auto loadA = [&](int kt) {           // issue 8 x global_load_dwordx4
    #pragma unroll
    for (int i = 0; i < 4; ++i) {
      int c = tid + 256 * i;
      int r = c >> 3, s = c & 7;
      const float* xr = x + (size_t)(h + 8 * (mt * BM + r)) * DM + kt * BK + s * 8;
      ap[2*i]   = *(const float4*)xr;
      ap[2*i+1] = *(const float4*)(xr + 4);
    }
  };
  auto stageB = [&](int kt, int buf) { // async global->LDS, linear dest
    const char* src = Bsrc0 + kt * TILE_B_BYTES;
    char* dst = (char*)Blds[buf];
    #pragma unroll
    for (int p = 0; p < 4; ++p)
      __builtin_amdgcn_global_load_lds((const void*)(src + p * 4096 + tid * 16),
                                       (void*)(dst + p * 4096 + wbase), 16, 0, 0);
  };
  auto writeA = [&](int buf) {         // convert + swizzled ds_write (T14 late half)
    char* dst = (char*)Alds[buf];
    #pragma unroll
    for (int i = 0; i < 4; ++i) {
      int c = tid + 256 * i;
      int r = c >> 3, s = c & 7;
      short8 sv;
      sv[0]=f2bf(ap[2*i].x); sv[1]=f2bf(ap[2*i].y);
      sv[2]=f2bf(ap[2*i].z); sv[3]=f2bf(ap[2*i].w);
      sv[4]=f2bf(ap[2*i+1].x); sv[5]=f2bf(ap[2*i+1].y);
      sv[6]=f2bf(ap[2*i+1].z); sv[7]=f2bf(ap[2*i+1].w);
      *(short8*)(dst + swz(r, s * 16)) = sv;
    }
  };

  f32x4 acc[4][4] = {};

  // --- prologue: stage tile 0 into buffer 0 ----------------------------
  loadA(0);
  stageB(0, 0);
  writeA(0);
  __syncthreads();

  // --- main loop: 1 barrier per K-step, loads fly under compute --------
  for (int kt = 0; kt < NKT; ++kt) {
    int cur = kt & 1, nxt = cur ^ 1;

    if (kt + 1 < NKT) {      // issue next tile's loads BEFORE compute
      loadA(kt + 1);
      stageB(kt + 1, nxt);
    }

    const char* Ab = (const char*)Alds[cur];
    const char* Bb = (const char*)Blds[cur];
    #pragma unroll
    for (int kk = 0; kk < 2; ++kk) {
      bf16x8 af[4], bfr[4];
      #pragma unroll
      for (int m = 0; m < 4; ++m) {
        int r = wr * 64 + m * 16 + (lane & 15);
        af[m] = *(const bf16x8*)(Ab + swz(r, kk * 64 + (lane >> 4) * 16));
      }
      #pragma unroll
      for (int n = 0; n < 4; ++n) {
        int r = wc * 64 + n * 16 + (lane & 15);
        bfr[n] = *(const bf16x8*)(Bb + swz(r, kk * 64 + (lane >> 4) * 16));
      }
      #pragma unroll
      for (int m = 0; m < 4; ++m)
        #pragma unroll
        for (int n = 0; n < 4; ++n)
          acc[m][n] = __builtin_amdgcn_mfma_f32_16x16x32_bf16(af[m], bfr[n], acc[m][n], 0, 0, 0);
    }

    if (kt + 1 < NKT) writeA(nxt);   // convert+ds_write after compute
    __syncthreads();                 // drains vmcnt+lgkm; next tile ready
  }

  // --- epilogue: C/D layout col = lane&15, row = (lane>>4)*4 + j -------
  int e0 = nt * BN + wc * 64 + (lane & 15);
  #pragma unroll
  for (int m = 0; m < 4; ++m) {
    int tbase = mt * BM + wr * 64 + m * 16 + ((lane >> 4) << 2);
    #pragma unroll
    for (int j = 0; j < 4; ++j) {
      int R = h + 8 * (tbase + j);
      float* orow = out + (size_t)R * DM + e0;
      #pragma unroll
      for (int n = 0; n < 4; ++n)
        orow[n * 16] = acc[m][n][j];
    }
  }
}

extern "C" void kernel_launch(void* const* d_in, const int* in_sizes, int n_in,
                              void* d_out, int out_size, void* d_ws, size_t ws_size,
                              hipStream_t stream) {
  const float* x   = (const float*)d_in[0];
  const float* w   = (const float*)d_in[1];
  const float* fcw = (const float*)d_in[2];
  float* out = (float*)d_out;
  short* Gt  = (short*)d_ws;   // 4 MiB pre-swizzled tile images

  hipLaunchKernelGGL(build_g_kernel, dim3((8 * DM * DM) / 256), dim3(256), 0, stream,
                     w, fcw, Gt);
  hipLaunchKernelGGL(gemm_kernel, dim3(8 * 64 * NT), dim3(256), 0, stream,
                     x, Gt, out);
}

// Round 4
// 79.735 us; speedup vs baseline: 1.6446x; 1.1141x over previous
//
#include <hip/hip_runtime.h>

typedef __attribute__((ext_vector_type(8))) __bf16  bf16x8;
typedef __attribute__((ext_vector_type(8))) short   short8;
typedef __attribute__((ext_vector_type(4))) float   f32x4;

#define DM   512
#define BM   256
#define BN   256
#define BK   64
#define NNT  2                 // n-tiles (512/256)
#define NKT  8                 // k-tiles (512/64)
#define TILEB 32768            // bytes per B tile image (256x64 bf16)

__device__ __forceinline__ short f2bf(float f) {
  union { float f; unsigned u; } v; v.f = f;
  unsigned r = v.u + 0x7fffu + ((v.u >> 16) & 1u);   // RNE
  return (short)(r >> 16);
}

// XOR swizzle within a [rows][64 bf16] tile (128B row stride).
__device__ __forceinline__ int swz(int r, int cbyte) {
  return (r * 128 + cbyte) ^ ((r & 7) << 4);
}

// Fold softmax(taps) + conv into per-head G[h][e][d], stored as pre-swizzled
// per-(h,nt,kt) 256x64 LDS tile images (linear gload_lds dest, swz on read).
__global__ void build_g_kernel(const float* __restrict__ w,
                               const float* __restrict__ fcw,
                               short* __restrict__ Gt) {
  int idx = blockIdx.x * 256 + threadIdx.x;   // 8*512*512
  int h = idx >> 18;
  int e = (idx >> 9) & 511;
  int d = idx & 511;
  float w0 = w[h*3+0], w1 = w[h*3+1], w2 = w[h*3+2];
  float mx = fmaxf(w0, fmaxf(w1, w2));
  float e0 = __expf(w0-mx), e1 = __expf(w1-mx), e2 = __expf(w2-mx);
  float inv = 1.0f / (e0 + e1 + e2);
  const float* row = fcw + e * DM;
  float acc = e1 * inv * row[d];
  if (d < DM-1) acc += e0 * inv * row[d+1];
  if (d > 0)    acc += e2 * inv * row[d-1];
  int nt = e >> 8, r = e & 255;
  int kt = d >> 6, c = d & 63;
  char* tile = (char*)Gt + (size_t)((h * NNT + nt) * NKT + kt) * TILEB;
  *(short*)(tile + swz(r, c * 2)) = f2bf(acc);
}

// y[R,e] = sum_d x[R,d] * G[R%8][e,d]; R = h + 8*t
__global__ __launch_bounds__(512, 2) void gemm_kernel(const float* __restrict__ x,
                                                      const short* __restrict__ Gt,
                                                      float* __restrict__ out) {
  int bid = blockIdx.x;          // 512 blocks
  int h  = bid & 7;              // head == XCD (512%8==0, bijective)
  int nt = (bid >> 3) & 1;       // bid, bid+8 share mt -> same-XCD x reuse
  int mt = bid >> 4;
  int tid  = threadIdx.x;
  int lane = tid & 63;
  int wid  = tid >> 6;
  int wr = wid >> 2, wc = wid & 3;   // 2x4 wave grid, 128x64 per wave

  __shared__ short Alds[2][BM * BK];   // 2 x 32 KiB swizzled
  __shared__ short Blds[2][BN * BK];   // 2 x 32 KiB swizzled

  const char* Bsrc0 = (const char*)Gt + (size_t)(h * NNT + nt) * NKT * TILEB;
  const float* Abase = x + (size_t)(h + 8 * (size_t)mt * BM) * DM;

  float4 ap[8];   // A prefetch (32 VGPR)

  auto loadA = [&](int kt) {
    #pragma unroll
    for (int p = 0; p < 4; ++p) {
      int r = (tid >> 3) + 64 * p;
      const float* xr = Abase + (size_t)r * 8 * DM + kt * BK + (tid & 7) * 8;
      ap[2*p]   = *(const float4*)xr;
      ap[2*p+1] = *(const float4*)(xr + 4);
    }
  };
  auto stageB = [&](int kt, int buf) {
    const char* src = Bsrc0 + kt * TILEB;
    char* dst = (char*)Blds[buf];
    #pragma unroll
    for (int p = 0; p < 4; ++p)
      __builtin_amdgcn_global_load_lds((const void*)(src + p * 8192 + tid * 16),
                                       (void*)(dst + p * 8192 + wid * 1024), 16, 0, 0);
  };
  auto writeA = [&](int buf) {
    char* dst = (char*)Alds[buf];
    #pragma unroll
    for (int p = 0; p < 4; ++p) {
      int r = (tid >> 3) + 64 * p;
      short8 sv;
      sv[0]=f2bf(ap[2*p].x);   sv[1]=f2bf(ap[2*p].y);
      sv[2]=f2bf(ap[2*p].z);   sv[3]=f2bf(ap[2*p].w);
      sv[4]=f2bf(ap[2*p+1].x); sv[5]=f2bf(ap[2*p+1].y);
      sv[6]=f2bf(ap[2*p+1].z); sv[7]=f2bf(ap[2*p+1].w);
      *(short8*)(dst + swz(r, (tid & 7) * 16)) = sv;
    }
  };

  f32x4 acc[8][4] = {};   // 128 VGPR accumulator, wave tile 128x64

  // prologue: tile 0 -> buf 0
  loadA(0);
  stageB(0, 0);
  writeA(0);
  __syncthreads();

  for (int kt = 0; kt < NKT; ++kt) {
    int cur = kt & 1, nxt = cur ^ 1;

    if (kt + 1 < NKT) {       // issue next tile's loads before compute
      loadA(kt + 1);
      stageB(kt + 1, nxt);
    }

    const char* Ap = (const char*)Alds[cur];
    const char* Bp = (const char*)Blds[cur];
    #pragma unroll
    for (int ks = 0; ks < 2; ++ks) {
      bf16x8 af[8], bfr[4];
      #pragma unroll
      for (int m = 0; m < 8; ++m)
        af[m] = *(const bf16x8*)(Ap + swz(wr*128 + m*16 + (lane & 15),
                                          ks*64 + (lane >> 4) * 16));
      #pragma unroll
      for (int n = 0; n < 4; ++n)
        bfr[n] = *(const bf16x8*)(Bp + swz(wc*64 + n*16 + (lane & 15),
                                           ks*64 + (lane >> 4) * 16));
      #pragma unroll
      for (int m = 0; m < 8; ++m)
        #pragma unroll
        for (int n = 0; n < 4; ++n)
          acc[m][n] = __builtin_amdgcn_mfma_f32_16x16x32_bf16(af[m], bfr[n], acc[m][n], 0, 0, 0);
    }

    if (kt + 1 < NKT) writeA(nxt);   // convert + ds_write after compute (T14)
    __syncthreads();                 // drains vmcnt+lgkm; next tile ready
  }

  // epilogue: C/D layout col = lane&15, row = (lane>>4)*4 + j
  int e0 = nt * BN + wc * 64 + (lane & 15);
  #pragma unroll
  for (int m = 0; m < 8; ++m) {
    int tq = mt * BM + wr * 128 + m * 16 + ((lane >> 4) << 2);
    #pragma unroll
    for (int j = 0; j < 4; ++j) {
      int R = h + 8 * (tq + j);
      float* orow = out + (size_t)R * DM + e0;
      #pragma unroll
      for (int n = 0; n < 4; ++n)
        orow[n * 16] = acc[m][n][j];
    }
  }
}

extern "C" void kernel_launch(void* const* d_in, const int* in_sizes, int n_in,
                              void* d_out, int out_size, void* d_ws, size_t ws_size,
                              hipStream_t stream) {
  const float* x   = (const float*)d_in[0];
  const float* w   = (const float*)d_in[1];
  const float* fcw = (const float*)d_in[2];
  float* out = (float*)d_out;
  short* Gt  = (short*)d_ws;   // 8*2*8 tiles * 32 KiB = 4 MiB pre-swizzled

  hipLaunchKernelGGL(build_g_kernel, dim3((8 * DM * DM) / 256), dim3(256), 0, stream,
                     w, fcw, Gt);
  hipLaunchKernelGGL(gemm_kernel, dim3(8 * 32 * NNT), dim3(512), 0, stream,
                     x, Gt, out);
}